// Round 4
// baseline (19127.818 us; speedup 1.0000x reference)
//
#include <hip/hip_runtime.h>

// 2-layer LSTM (H=256, B=512, T=512) + FC. 32 batch-groups x 4 gate-split
// blocks (128 CUs), weights register/LDS-resident (validated r2/r3).
//
// Round-3 lesson: tagged fence-free exchange works (3.87ms) but every poll
// is a device-coherence-point round trip (~900+cy) because group members sit
// on 4 different XCDs. Round-4:
//  (a) XCD-local groups: members at b = xcd + 8*j + 32*gi share one L2 under
//      the round-robin dispatch map. Writers: plain store (dirty in shared
//      L2) + relaxed agent-scope mirror store (MALL, correctness anchor).
//      Readers: poll sc0-only (L2-local, ~250cy); after 24 failed tries fall
//      back to sc0+sc1 mirror reads (round-3 behavior). Tags make a wrong
//      mapping slow, never incorrect.
//  (b) h1(t-2) loads issued BEFORE the h0 poll (a full phase of slack);
//      vmcnt drains oldest-first so the h0 wait covers them; validate after
//      L1 compute. Removes one serial round trip per phase.

#define Hdim 256
#define Tdim 512
#define NB 16
#define NGRP 32

typedef float f32x4 __attribute__((ext_vector_type(4)));
typedef _Float16 f16x8 __attribute__((ext_vector_type(8)));

#define SLOTD (NGRP * NB * 256)        // dwords per ring slot (512 KB)
#define TAGOF(s) ((unsigned)((s) + 1)) // tag of step s (1..512; poison 0xAAAA safe)

__device__ __forceinline__ float sigm(float x){ return 1.0f/(1.0f + __expf(-x)); }
__device__ __forceinline__ float tanh_fast(float x){
  float ax = fabsf(x);
  float e = __expf(-2.0f*ax);
  float r = (1.0f - e)/(1.0f + e);
  return copysignf(r, x);
}

// h position permutation (validated r1-r3): contiguous 8 positions at
// 32*kc+8*gq hold logical k = 32kc+4gq+{0..3,16..19} = one A/B fragment.
__device__ __forceinline__ int pcol(int k){
  return (k&3) | (((k>>4)&1)<<2) | (((k>>2)&3)<<3) | ((k>>5)<<5);
}
__device__ __forceinline__ int pcol_inv(int q){
  return (q&3) | (((q>>3)&3)<<2) | (((q>>2)&1)<<4) | ((q>>5)<<5);
}

__device__ __forceinline__ f16x8 load_wfrag(const float* Wrow, int k0){
  float4 a = *(const float4*)(Wrow + k0);
  float4 b = *(const float4*)(Wrow + k0 + 16);
  f16x8 r;
  r[0]=(_Float16)a.x; r[1]=(_Float16)a.y; r[2]=(_Float16)a.z; r[3]=(_Float16)a.w;
  r[4]=(_Float16)b.x; r[5]=(_Float16)b.y; r[6]=(_Float16)b.z; r[7]=(_Float16)b.w;
  return r;
}

// mirror store: relaxed agent-scope -> device coherence point (r3-validated)
__device__ __forceinline__ void st_mall(unsigned* p, unsigned v){
  __hip_atomic_store(p, v, __ATOMIC_RELAXED, __HIP_MEMORY_SCOPE_AGENT);
}

// Issue+wait+validate 8 epoch-tagged fragments (64 dwords) for this lane.
// MALL=false: sc0 only (XCD-L2 local). MALL=true: sc0 sc1 (coherence point).
template<bool MALL>
__device__ __forceinline__ bool try_read_frags(const unsigned* base, unsigned tag, f16x8* out){
  uint4 ra[8], rb[8];
#pragma unroll
  for (int kc=0; kc<8; ++kc){
    const unsigned* pp = base + 32*kc;
    if (MALL){
      asm volatile("global_load_dwordx4 %0, %1, off sc0 sc1" : "=v"(ra[kc]) : "v"(pp));
      asm volatile("global_load_dwordx4 %0, %1, off sc0 sc1" : "=v"(rb[kc]) : "v"(pp+4));
    } else {
      asm volatile("global_load_dwordx4 %0, %1, off sc0" : "=v"(ra[kc]) : "v"(pp));
      asm volatile("global_load_dwordx4 %0, %1, off sc0" : "=v"(rb[kc]) : "v"(pp+4));
    }
  }
  asm volatile("s_waitcnt vmcnt(0)" ::: "memory");
  __builtin_amdgcn_sched_barrier(0);   // rule #18
  unsigned bad = 0;
#pragma unroll
  for (int kc=0; kc<8; ++kc){
    bad |= ((ra[kc].x>>16)^tag) | ((ra[kc].y>>16)^tag) | ((ra[kc].z>>16)^tag) | ((ra[kc].w>>16)^tag)
         | ((rb[kc].x>>16)^tag) | ((rb[kc].y>>16)^tag) | ((rb[kc].z>>16)^tag) | ((rb[kc].w>>16)^tag);
    uint4 pk;
    pk.x = (ra[kc].x & 0xffffu) | (ra[kc].y << 16);
    pk.y = (ra[kc].z & 0xffffu) | (ra[kc].w << 16);
    pk.z = (rb[kc].x & 0xffffu) | (rb[kc].y << 16);
    pk.w = (rb[kc].z & 0xffffu) | (rb[kc].w << 16);
    out[kc] = __builtin_bit_cast(f16x8, pk);
  }
  return !__any((int)bad);
}

// fast-path poll with bounded mirror fallback; never hangs, never silently
// proceeds without attempting the coherent path.
__device__ __forceinline__ void read_frags_fb(const unsigned* baseF, const unsigned* baseM,
                                              unsigned tag, f16x8* out){
  for (int tr=0; tr<24; ++tr) if (try_read_frags<false>(baseF, tag, out)) return;
  long it = 0;
  while (!try_read_frags<true>(baseM, tag, out) && ++it < 60000) {}
}

__global__ __launch_bounds__(256, 1) void lstm2_xl(
    const float* __restrict__ x,
    const float* __restrict__ Wih0, const float* __restrict__ Whh0,
    const float* __restrict__ bih0, const float* __restrict__ bhh0,
    const float* __restrict__ Wih1, const float* __restrict__ Whh1,
    const float* __restrict__ bih1, const float* __restrict__ bhh1,
    const float* __restrict__ Wfc,  const float* __restrict__ bfc,
    float* __restrict__ out, unsigned* __restrict__ ws, unsigned mirror_off)
{
  __shared__ f16x8 w2h_lds[4*4*8*64];   // Whh1 slice, frag order, 128 KB

  const int b   = blockIdx.x;
  // XCD-local grouping under round-robin dispatch: members share b&7
  const int j   = (b >> 3) & 3;         // group member: h-cols [64j, 64j+64)
  const int grp = (b & 7) * 4 + (b >> 5);
  const int tid = threadIdx.x;
  const int w   = tid >> 6;
  const int L   = tid & 63;
  const int p   = L & 15;
  const int gq  = L >> 4;
  const int R0  = grp * NB;

  unsigned* h0f = ws;                   // fast rings: [3][NGRP][NB][256]
  unsigned* h1f = ws + 3*(size_t)SLOTD;
  unsigned* h0m = ws + mirror_off;      // mirror rings (alias fast if no space)
  unsigned* h1m = ws + mirror_off + 3*(size_t)SLOTD;

  // ---- weights: Whh0, Wih1 -> registers; Whh1 -> LDS (validated r2/r3)
  f16x8 W1[4][8], W2i[4][8];
  float bs1[4], wx0[4], bs2[4];
#pragma unroll
  for (int gate=0; gate<4; ++gate){
    const int gr = 256*gate + 64*j + 16*w + p;
    const float* r0 = Whh0 + (size_t)gr*Hdim;
    const float* r1 = Wih1 + (size_t)gr*Hdim;
    const float* r2 = Whh1 + (size_t)gr*Hdim;
#pragma unroll
    for (int kc=0; kc<8; ++kc){
      W1[gate][kc]  = load_wfrag(r0, 32*kc + 4*gq);
      W2i[gate][kc] = load_wfrag(r1, 32*kc + 4*gq);
      w2h_lds[((w*4+gate)*8+kc)*64 + L] = load_wfrag(r2, 32*kc + 4*gq);
    }
    bs1[gate] = bih0[gr] + bhh0[gr];
    wx0[gate] = Wih0[gr];
    bs2[gate] = bih1[gr] + bhh1[gr];
  }
  // each wave reads only its own w2h_lds region: no barrier needed

  const int myq = pcol(64*j + 16*w + p);
  const int grpoff = grp * (NB*256);
  const int laneoff = grpoff + p*256 + 8*gq;
  float c0[4] = {0,0,0,0};
  float c1[4] = {0,0,0,0};

  for (int t=0; t<=Tdim; ++t){
    f16x8 a0[8], a1[8];
    const bool has_h1 = (t > 1);

    // ---- (b) issue h1(t-2) fast loads FIRST: a phase of slack, and the h0
    // poll's vmcnt(0) drains them for free (oldest-first).
    uint4 e1a[8], e1b[8];
    const unsigned* s1f = h1f + (size_t)(has_h1 ? (t-2)%3 : 0)*SLOTD + laneoff;
    if (has_h1){
#pragma unroll
      for (int kc=0; kc<8; ++kc){
        const unsigned* pp = s1f + 32*kc;
        asm volatile("global_load_dwordx4 %0, %1, off sc0" : "=v"(e1a[kc]) : "v"(pp));
        asm volatile("global_load_dwordx4 %0, %1, off sc0" : "=v"(e1b[kc]) : "v"(pp+4));
      }
    }

    // ---- h0(t-1): fast poll + mirror fallback
    if (t){
      read_frags_fb(h0f + (size_t)((t-1)%3)*SLOTD + laneoff,
                    h0m + (size_t)((t-1)%3)*SLOTD + laneoff, TAGOF(t-1), a0);
    }

    // ================= layer 1, step t =================
    if (t < Tdim){
      float xv[4];
#pragma unroll
      for (int u=0; u<4; ++u) xv[u] = x[(size_t)(R0 + 4*gq + u)*Tdim + t];
      f32x4 acc[4];
#pragma unroll
      for (int gate=0; gate<4; ++gate)
#pragma unroll
        for (int u=0; u<4; ++u) acc[gate][u] = bs1[gate] + xv[u]*wx0[gate];
      if (t){
#pragma unroll
        for (int kc=0; kc<8; ++kc)
#pragma unroll
          for (int gate=0; gate<4; ++gate)
            acc[gate] = __builtin_amdgcn_mfma_f32_16x16x32_f16(a0[kc], W1[gate][kc], acc[gate], 0,0,0);
      }
      unsigned* dF = h0f + (size_t)(t%3)*SLOTD + grpoff + myq;
      unsigned* dM = h0m + (size_t)(t%3)*SLOTD + grpoff + myq;
      const unsigned tg = TAGOF(t) << 16;
#pragma unroll
      for (int u=0; u<4; ++u){
        float iv = sigm(acc[0][u]);
        float fv = sigm(acc[1][u]);
        float gv = tanh_fast(acc[2][u]);
        float ov = sigm(acc[3][u]);
        c0[u] = fv*c0[u] + iv*gv;
        unsigned hv = tg | __builtin_bit_cast(unsigned short, (_Float16)(ov*tanh_fast(c0[u])));
        dF[(4*gq+u)*256] = hv;         // plain store: dirty in shared XCD L2
        st_mall(&dM[(4*gq+u)*256], hv);// mirror: device coherence point
      }
    }

    // ================= layer 2, step t-1 =================
    if (t){
      if (has_h1){
        // validate the early-issued h1 loads; on mismatch, normal fallback
        asm volatile("s_waitcnt vmcnt(0)" ::: "memory");
        __builtin_amdgcn_sched_barrier(0);
        unsigned bad = 0;
#pragma unroll
        for (int kc=0; kc<8; ++kc){
          const unsigned tag = TAGOF(t-2);
          bad |= ((e1a[kc].x>>16)^tag) | ((e1a[kc].y>>16)^tag) | ((e1a[kc].z>>16)^tag) | ((e1a[kc].w>>16)^tag)
               | ((e1b[kc].x>>16)^tag) | ((e1b[kc].y>>16)^tag) | ((e1b[kc].z>>16)^tag) | ((e1b[kc].w>>16)^tag);
          uint4 pk;
          pk.x = (e1a[kc].x & 0xffffu) | (e1a[kc].y << 16);
          pk.y = (e1a[kc].z & 0xffffu) | (e1a[kc].w << 16);
          pk.z = (e1b[kc].x & 0xffffu) | (e1b[kc].y << 16);
          pk.w = (e1b[kc].z & 0xffffu) | (e1b[kc].w << 16);
          a1[kc] = __builtin_bit_cast(f16x8, pk);
        }
        if (__any((int)bad)){
          read_frags_fb(s1f, h1m + (size_t)((t-2)%3)*SLOTD + laneoff, TAGOF(t-2), a1);
        }
      }
      f32x4 acc[4];
#pragma unroll
      for (int gate=0; gate<4; ++gate)
#pragma unroll
        for (int u=0; u<4; ++u) acc[gate][u] = bs2[gate];
#pragma unroll
      for (int kc=0; kc<8; ++kc)
#pragma unroll
        for (int gate=0; gate<4; ++gate)
          acc[gate] = __builtin_amdgcn_mfma_f32_16x16x32_f16(a0[kc], W2i[gate][kc], acc[gate], 0,0,0);
      if (has_h1){
#pragma unroll
        for (int kc=0; kc<8; ++kc)
#pragma unroll
          for (int gate=0; gate<4; ++gate){
            f16x8 wf = w2h_lds[((w*4+gate)*8+kc)*64 + L];
            acc[gate] = __builtin_amdgcn_mfma_f32_16x16x32_f16(a1[kc], wf, acc[gate], 0,0,0);
          }
      }
      unsigned* dF = h1f + (size_t)((t-1)%3)*SLOTD + grpoff + myq;
      unsigned* dM = h1m + (size_t)((t-1)%3)*SLOTD + grpoff + myq;
      const unsigned tg1 = TAGOF(t-1) << 16;
#pragma unroll
      for (int u=0; u<4; ++u){
        float iv = sigm(acc[0][u]);
        float fv = sigm(acc[1][u]);
        float gv = tanh_fast(acc[2][u]);
        float ov = sigm(acc[3][u]);
        c1[u] = fv*c1[u] + iv*gv;
        unsigned hv = tg1 | __builtin_bit_cast(unsigned short, (_Float16)(ov*tanh_fast(c1[u])));
        dF[(4*gq+u)*256] = hv;
        st_mall(&dM[(4*gq+u)*256], hv);
      }
    }
  }

  // ---- FC epilogue: wave 0 of member j==0 reduces the group's 16 rows.
  // Fragment reads give lane (p,gq) the 64 positions {32kc+8gq+e} of row p;
  // reduce over the 4 gq-lanes sharing p via shfl_xor(16|32).
  if (j == 0 && w == 0){
    const int fslot = (Tdim-1)%3;
    f16x8 hf[8];
    read_frags_fb(h1f + (size_t)fslot*SLOTD + laneoff,
                  h1m + (size_t)fslot*SLOTD + laneoff, TAGOF(Tdim-1), hf);
    float s = 0.0f;
#pragma unroll
    for (int kc=0; kc<8; ++kc)
#pragma unroll
      for (int e=0; e<8; ++e){
        int q = 32*kc + 8*gq + e;
        s += (float)hf[kc][e] * Wfc[pcol_inv(q)];
      }
    s += __shfl_xor(s, 16);
    s += __shfl_xor(s, 32);
    if (gq == 0) out[R0 + p] = s + bfc[0];
  }
}

extern "C" void kernel_launch(void* const* d_in, const int* in_sizes, int n_in,
                              void* d_out, int out_size, void* d_ws, size_t ws_size,
                              hipStream_t stream) {
  // fast rings (3MB) + mirror rings (3MB) if workspace allows; else alias
  // (aliased mode == round-3 semantics: atomic store wins, tags still valid)
  const size_t need = 12ull * SLOTD * 4ull;
  const unsigned mirror_off = (ws_size >= need) ? 6u*(unsigned)SLOTD : 0u;
  lstm2_xl<<<dim3(128), dim3(256), 0, stream>>>(
      (const float*)d_in[0],
      (const float*)d_in[1], (const float*)d_in[2],
      (const float*)d_in[3], (const float*)d_in[4],
      (const float*)d_in[5], (const float*)d_in[6],
      (const float*)d_in[7], (const float*)d_in[8],
      (const float*)d_in[9], (const float*)d_in[10],
      (float*)d_out, (unsigned*)d_ws, mirror_off);
}

// Round 7
// 5365.240 us; speedup vs baseline: 3.5651x; 3.5651x over previous
//
#include <hip/hip_runtime.h>

// 2-layer LSTM (H=256, B=512, T=512) + FC. 32 batch-groups x 4 gate-split
// blocks (128 CUs). Weights: Whh0,Wih1 in registers, Whh1 in LDS.
// Exchange: r3-VALIDATED path only — relaxed agent atomic stores (MALL),
// sc0+sc1 tagged reads, per-word epoch tags, mod-3 ring. No sentinels, no
// LDS staging (r5's unproven machinery removed for bisection).
// Round-6 deltas vs r3 (each independently validated):
//  (a) amdgpu_waves_per_eu(1,1): unlock 512-VGPR budget. r2-r5 ran with
//      VGPR_Count 212-256 < the 256 weight VGPRs alone -> weight frags
//      spill-reloaded from scratch every phase (r3's 1.06GB FETCH).
//  (b) r4-validated early h1(t-2) issue before the h0 poll (vmcnt drains
//      them under the poll); validate after L1; bounded retry fallback.
// (Resubmission of round 6: bench never ran — GPU acquisition timeout.)

#define Hdim 256
#define Tdim 512
#define NB 16
#define NGRP 32

typedef float f32x4 __attribute__((ext_vector_type(4)));
typedef _Float16 f16x8 __attribute__((ext_vector_type(8)));

#define SLOTD (NGRP * NB * 256)        // dwords per ring slot (512 KB)
#define TAGOF(s) ((unsigned)((s) + 1)) // 1..513; poison 0xAAAA never aliases

__device__ __forceinline__ float sigm(float x){ return 1.0f/(1.0f + __expf(-x)); }
__device__ __forceinline__ float tanh_fast(float x){
  float ax = fabsf(x);
  float e = __expf(-2.0f*ax);
  float r = (1.0f - e)/(1.0f + e);
  return copysignf(r, x);
}

// position permutation (validated r1-r4): contiguous 8 positions at
// 32*kc+8*gq hold logical k = 32kc+4gq+{0..3,16..19} = one A/B fragment.
__device__ __forceinline__ int pcol(int k){
  return (k&3) | (((k>>4)&1)<<2) | (((k>>2)&3)<<3) | ((k>>5)<<5);
}
__device__ __forceinline__ int pcol_inv(int q){
  return (q&3) | (((q>>3)&3)<<2) | (((q>>2)&1)<<4) | ((q>>5)<<5);
}

__device__ __forceinline__ f16x8 load_wfrag(const float* Wrow, int k0){
  float4 a = *(const float4*)(Wrow + k0);
  float4 b = *(const float4*)(Wrow + k0 + 16);
  f16x8 r;
  r[0]=(_Float16)a.x; r[1]=(_Float16)a.y; r[2]=(_Float16)a.z; r[3]=(_Float16)a.w;
  r[4]=(_Float16)b.x; r[5]=(_Float16)b.y; r[6]=(_Float16)b.z; r[7]=(_Float16)b.w;
  return r;
}

__device__ __forceinline__ void st_mall(unsigned* p, unsigned v){
  __hip_atomic_store(p, v, __ATOMIC_RELAXED, __HIP_MEMORY_SCOPE_AGENT);
}

#define LD4(dst, ptr) asm volatile("global_load_dwordx4 %0, %1, off sc0 sc1" : "=v"(dst) : "v"(ptr))
#define VM0() do { asm volatile("s_waitcnt vmcnt(0)" ::: "memory"); __builtin_amdgcn_sched_barrier(0); } while(0)

// r3-validated: issue+wait+validate 8 epoch-tagged fragments (64 dwords).
__device__ __forceinline__ bool try_read_frags(const unsigned* base, unsigned tag, f16x8* out){
  uint4 ra[8], rb[8];
#pragma unroll
  for (int kc=0; kc<8; ++kc){
    const unsigned* pp = base + 32*kc;
    LD4(ra[kc], pp); LD4(rb[kc], pp+4);
  }
  VM0();
  unsigned bad = 0;
#pragma unroll
  for (int kc=0; kc<8; ++kc){
    bad |= ((ra[kc].x>>16)^tag) | ((ra[kc].y>>16)^tag) | ((ra[kc].z>>16)^tag) | ((ra[kc].w>>16)^tag)
         | ((rb[kc].x>>16)^tag) | ((rb[kc].y>>16)^tag) | ((rb[kc].z>>16)^tag) | ((rb[kc].w>>16)^tag);
    uint4 pk;
    pk.x = (ra[kc].x & 0xffffu) | (ra[kc].y << 16);
    pk.y = (ra[kc].z & 0xffffu) | (ra[kc].w << 16);
    pk.z = (rb[kc].x & 0xffffu) | (rb[kc].y << 16);
    pk.w = (rb[kc].z & 0xffffu) | (rb[kc].w << 16);
    out[kc] = __builtin_bit_cast(f16x8, pk);
  }
  return !__any((int)bad);
}

__global__ __launch_bounds__(256, 1) __attribute__((amdgpu_waves_per_eu(1,1)))
void lstm2_r6(
    const float* __restrict__ x,
    const float* __restrict__ Wih0, const float* __restrict__ Whh0,
    const float* __restrict__ bih0, const float* __restrict__ bhh0,
    const float* __restrict__ Wih1, const float* __restrict__ Whh1,
    const float* __restrict__ bih1, const float* __restrict__ bhh1,
    const float* __restrict__ Wfc,  const float* __restrict__ bfc,
    float* __restrict__ out, unsigned* __restrict__ ws)
{
  __shared__ f16x8 w2h_lds[4*4*8*64];   // Whh1 slice, frag order, 128 KB

  const int b   = blockIdx.x;
  const int j   = b & 3;                // group member: h-cols [64j, 64j+64)
  const int grp = b >> 2;
  const int tid = threadIdx.x;
  const int w   = tid >> 6;
  const int L   = tid & 63;
  const int p   = L & 15;
  const int gq  = L >> 4;
  const int R0  = grp * NB;

  unsigned* h0r = ws;                   // [3][NGRP][NB][256] dwords
  unsigned* h1r = ws + 3*(size_t)SLOTD;

  // ---- weights: Whh0, Wih1 -> registers; Whh1 -> LDS (validated r2-r4)
  f16x8 W1[4][8], W2i[4][8];
  float bs1[4], wx0[4], bs2[4];
#pragma unroll
  for (int gate=0; gate<4; ++gate){
    const int gr = 256*gate + 64*j + 16*w + p;
    const float* r0 = Whh0 + (size_t)gr*Hdim;
    const float* r1 = Wih1 + (size_t)gr*Hdim;
    const float* r2 = Whh1 + (size_t)gr*Hdim;
#pragma unroll
    for (int kc=0; kc<8; ++kc){
      W1[gate][kc]  = load_wfrag(r0, 32*kc + 4*gq);
      W2i[gate][kc] = load_wfrag(r1, 32*kc + 4*gq);
      w2h_lds[((w*4+gate)*8+kc)*64 + L] = load_wfrag(r2, 32*kc + 4*gq);
    }
    bs1[gate] = bih0[gr] + bhh0[gr];
    wx0[gate] = Wih0[gr];
    bs2[gate] = bih1[gr] + bhh1[gr];
  }
  // each wave reads only its own w2h_lds region: no barrier needed

  const int myq = pcol(64*j + 16*w + p);
  const int grpoff = grp * (NB*256);
  const int laneoff = grpoff + p*256 + 8*gq;
  float c0[4] = {0,0,0,0};
  float c1[4] = {0,0,0,0};

  for (int t=0; t<=Tdim; ++t){
    f16x8 a0[8], a1[8];
    const bool has_h1 = (t > 1);

    // ---- (b) issue h1(t-2) loads FIRST (r4-validated): the h0 poll's
    // vmcnt(0) drains them; validate after L1 compute.
    uint4 e1a[8], e1b[8];
    const unsigned* s1 = h1r + (size_t)(has_h1 ? (t-2)%3 : 0)*SLOTD + laneoff;
    if (has_h1){
#pragma unroll
      for (int kc=0; kc<8; ++kc){
        const unsigned* pp = s1 + 32*kc;
        LD4(e1a[kc], pp); LD4(e1b[kc], pp+4);
      }
    }

    // ---- h0(t-1): r3-validated full-read poll
    if (t){
      const unsigned* s0 = h0r + (size_t)((t-1)%3)*SLOTD + laneoff;
      long it = 0; bool ok;
      do { ok = try_read_frags(s0, TAGOF(t-1), a0); } while (!ok && ++it < 60000);
    }

    // ================= layer 1, step t =================
    if (t < Tdim){
      float xv[4];
#pragma unroll
      for (int u=0; u<4; ++u) xv[u] = x[(size_t)(R0 + 4*gq + u)*Tdim + t];
      f32x4 acc[4];
#pragma unroll
      for (int gate=0; gate<4; ++gate)
#pragma unroll
        for (int u=0; u<4; ++u) acc[gate][u] = bs1[gate] + xv[u]*wx0[gate];
      if (t){
#pragma unroll
        for (int kc=0; kc<8; ++kc)
#pragma unroll
          for (int gate=0; gate<4; ++gate)
            acc[gate] = __builtin_amdgcn_mfma_f32_16x16x32_f16(a0[kc], W1[gate][kc], acc[gate], 0,0,0);
      }
      unsigned* dst = h0r + (size_t)(t%3)*SLOTD + grpoff + myq;
      const unsigned tg = TAGOF(t) << 16;
#pragma unroll
      for (int u=0; u<4; ++u){
        float iv = sigm(acc[0][u]);
        float fv = sigm(acc[1][u]);
        float gv = tanh_fast(acc[2][u]);
        float ov = sigm(acc[3][u]);
        c0[u] = fv*c0[u] + iv*gv;
        st_mall(&dst[(4*gq+u)*256], tg | __builtin_bit_cast(unsigned short, (_Float16)(ov*tanh_fast(c0[u]))));
      }
    }

    // ================= layer 2, step t-1 =================
    if (t){
      if (has_h1){
        // validate the early-issued h1 loads; on mismatch, bounded retry
        VM0();
        const unsigned tag = TAGOF(t-2);
        unsigned bad = 0;
#pragma unroll
        for (int kc=0; kc<8; ++kc){
          bad |= ((e1a[kc].x>>16)^tag) | ((e1a[kc].y>>16)^tag) | ((e1a[kc].z>>16)^tag) | ((e1a[kc].w>>16)^tag)
               | ((e1b[kc].x>>16)^tag) | ((e1b[kc].y>>16)^tag) | ((e1b[kc].z>>16)^tag) | ((e1b[kc].w>>16)^tag);
          uint4 pk;
          pk.x = (e1a[kc].x & 0xffffu) | (e1a[kc].y << 16);
          pk.y = (e1a[kc].z & 0xffffu) | (e1a[kc].w << 16);
          pk.z = (e1b[kc].x & 0xffffu) | (e1b[kc].y << 16);
          pk.w = (e1b[kc].z & 0xffffu) | (e1b[kc].w << 16);
          a1[kc] = __builtin_bit_cast(f16x8, pk);
        }
        if (__any((int)bad)){
          long it = 0; bool ok;
          do { ok = try_read_frags(s1, tag, a1); } while (!ok && ++it < 60000);
        }
      }
      f32x4 acc[4];
#pragma unroll
      for (int gate=0; gate<4; ++gate)
#pragma unroll
        for (int u=0; u<4; ++u) acc[gate][u] = bs2[gate];
#pragma unroll
      for (int kc=0; kc<8; ++kc)
#pragma unroll
        for (int gate=0; gate<4; ++gate)
          acc[gate] = __builtin_amdgcn_mfma_f32_16x16x32_f16(a0[kc], W2i[gate][kc], acc[gate], 0,0,0);
      if (has_h1){
#pragma unroll
        for (int kc=0; kc<8; ++kc)
#pragma unroll
          for (int gate=0; gate<4; ++gate){
            f16x8 wf = w2h_lds[((w*4+gate)*8+kc)*64 + L];
            acc[gate] = __builtin_amdgcn_mfma_f32_16x16x32_f16(a1[kc], wf, acc[gate], 0,0,0);
          }
      }
      unsigned* dst1 = h1r + (size_t)((t-1)%3)*SLOTD + grpoff + myq;
      const unsigned tg1 = TAGOF(t-1) << 16;
#pragma unroll
      for (int u=0; u<4; ++u){
        float iv = sigm(acc[0][u]);
        float fv = sigm(acc[1][u]);
        float gv = tanh_fast(acc[2][u]);
        float ov = sigm(acc[3][u]);
        c1[u] = fv*c1[u] + iv*gv;
        st_mall(&dst1[(4*gq+u)*256], tg1 | __builtin_bit_cast(unsigned short, (_Float16)(ov*tanh_fast(c1[u]))));
      }
    }
  }

  // ---- FC epilogue (r4-validated): member 0, wave 0 reduces 16 batch rows
  if (j == 0 && w == 0){
    const unsigned* src = h1r + (size_t)((Tdim-1)%3)*SLOTD + laneoff;
    const unsigned want = TAGOF(Tdim-1);
    f16x8 hf[8];
    long it = 0; bool ok;
    do { ok = try_read_frags(src, want, hf); } while (!ok && ++it < 60000);
    float s = 0.0f;
#pragma unroll
    for (int kc=0; kc<8; ++kc)
#pragma unroll
      for (int e=0; e<8; ++e){
        int q = 32*kc + 8*gq + e;
        s += (float)hf[kc][e] * Wfc[pcol_inv(q)];
      }
    s += __shfl_xor(s, 16);
    s += __shfl_xor(s, 32);
    if (gq == 0) out[R0 + p] = s + bfc[0];
  }
}

extern "C" void kernel_launch(void* const* d_in, const int* in_sizes, int n_in,
                              void* d_out, int out_size, void* d_ws, size_t ws_size,
                              hipStream_t stream) {
  // tags self-validate against 0xAA poison (1..513 != 0xAAAA); no memset,
  // no sync APIs (graph-capture safe)
  lstm2_r6<<<dim3(128), dim3(256), 0, stream>>>(
      (const float*)d_in[0],
      (const float*)d_in[1], (const float*)d_in[2],
      (const float*)d_in[3], (const float*)d_in[4],
      (const float*)d_in[5], (const float*)d_in[6],
      (const float*)d_in[7], (const float*)d_in[8],
      (const float*)d_in[9], (const float*)d_in[10],
      (float*)d_out, (unsigned*)d_ws);
}

// Round 9
// 4307.475 us; speedup vs baseline: 4.4406x; 1.2456x over previous
//
#include <hip/hip_runtime.h>

// 2-layer LSTM (H=256, B=512, T=512) + FC. 32 batch-groups x 4 gate-split
// blocks (128 CUs). Weights: Whh0,Wih1 in registers (256-VGPR cap, some
// spill accepted), Whh1 in LDS. Exchange: r3-validated MALL path — relaxed
// agent atomic stores, sc0+sc1 tagged reads, per-word epoch tags, mod-3
// ring. Round-8 deltas vs r3:
//  (1) cheap PRE-POLL: spin on 4 probe dwords (one per member) until tagged,
//      then do the full validated read (r3 loop unchanged). Cuts poll-retry
//      traffic ~64x and retry latency ~3x.
//  (2) PLAIN column layout (pcol dropped): reader needs 2x dwordx4 per frag
//      either way (+16 hi-half); plain order coalesces writer lines (~2x
//      less write traffic).
//  (3) h1 poll moved after the W2i chain (hidden under a0-dependent MFMAs).
//  r6's early-h1-issue REVERTED (measured −38%: premature reads -> retries).
// (Resubmission: round-8 bench never ran — GPU acquisition timeout.)

#define Hdim 256
#define Tdim 512
#define NB 16
#define NGRP 32

typedef float f32x4 __attribute__((ext_vector_type(4)));
typedef _Float16 f16x8 __attribute__((ext_vector_type(8)));

#define SLOTD (NGRP * NB * 256)        // dwords per ring slot (512 KB)
#define TAGOF(s) ((unsigned)((s) + 1)) // 1..513; poison 0xAAAA never aliases

__device__ __forceinline__ float sigm(float x){ return 1.0f/(1.0f + __expf(-x)); }
__device__ __forceinline__ float tanh_fast(float x){
  float ax = fabsf(x);
  float e = __expf(-2.0f*ax);
  float r = (1.0f - e)/(1.0f + e);
  return copysignf(r, x);
}

__device__ __forceinline__ f16x8 load_wfrag(const float* Wrow, int k0){
  float4 a = *(const float4*)(Wrow + k0);
  float4 b = *(const float4*)(Wrow + k0 + 16);
  f16x8 r;
  r[0]=(_Float16)a.x; r[1]=(_Float16)a.y; r[2]=(_Float16)a.z; r[3]=(_Float16)a.w;
  r[4]=(_Float16)b.x; r[5]=(_Float16)b.y; r[6]=(_Float16)b.z; r[7]=(_Float16)b.w;
  return r;
}

__device__ __forceinline__ void st_mall(unsigned* p, unsigned v){
  __hip_atomic_store(p, v, __ATOMIC_RELAXED, __HIP_MEMORY_SCOPE_AGENT);
}

#define LD4(dst, ptr) asm volatile("global_load_dwordx4 %0, %1, off sc0 sc1" : "=v"(dst) : "v"(ptr))
#define LD1(dst, ptr) asm volatile("global_load_dword %0, %1, off sc0 sc1" : "=v"(dst) : "v"(ptr))
#define VM0() do { asm volatile("s_waitcnt vmcnt(0)" ::: "memory"); __builtin_amdgcn_sched_barrier(0); } while(0)

// (1) cheap readiness probe: 4 dwords, one per member slice, spread across
// writer waves (w'=p&3) and writer lanes (p''=p>>2). Heuristic only — the
// full tagged read below remains the correctness anchor.
__device__ __forceinline__ void prepoll(const unsigned* rowbase, unsigned tag, int p){
  const int off = 16*(p&3) + (p>>2);
  long it = 0;
  for (;;){
    unsigned v0,v1,v2,v3;
    LD1(v0, rowbase + off);
    LD1(v1, rowbase + 64 + off);
    LD1(v2, rowbase + 128 + off);
    LD1(v3, rowbase + 192 + off);
    VM0();
    unsigned bad = ((v0>>16)^tag)|((v1>>16)^tag)|((v2>>16)^tag)|((v3>>16)^tag);
    if (!__any((int)bad)) return;
    if (++it > 30000) return;   // bounded; full read still validates
  }
}

// full validated fragment read, PLAIN layout: frag kc = dwords
// [32kc+4gq .. +3] (lo) and [32kc+4gq+16 .. +19] (hi) of row p.
__device__ __forceinline__ bool try_read_frags(const unsigned* base, unsigned tag, f16x8* out){
  uint4 ra[8], rb[8];
#pragma unroll
  for (int kc=0; kc<8; ++kc){
    const unsigned* pp = base + 32*kc;
    LD4(ra[kc], pp); LD4(rb[kc], pp+16);
  }
  VM0();
  unsigned bad = 0;
#pragma unroll
  for (int kc=0; kc<8; ++kc){
    bad |= ((ra[kc].x>>16)^tag) | ((ra[kc].y>>16)^tag) | ((ra[kc].z>>16)^tag) | ((ra[kc].w>>16)^tag)
         | ((rb[kc].x>>16)^tag) | ((rb[kc].y>>16)^tag) | ((rb[kc].z>>16)^tag) | ((rb[kc].w>>16)^tag);
    uint4 pk;
    pk.x = (ra[kc].x & 0xffffu) | (ra[kc].y << 16);
    pk.y = (ra[kc].z & 0xffffu) | (ra[kc].w << 16);
    pk.z = (rb[kc].x & 0xffffu) | (rb[kc].y << 16);
    pk.w = (rb[kc].z & 0xffffu) | (rb[kc].w << 16);
    out[kc] = __builtin_bit_cast(f16x8, pk);
  }
  return !__any((int)bad);
}

__global__ __launch_bounds__(256, 1) __attribute__((amdgpu_waves_per_eu(1,1)))
void lstm2_r8(
    const float* __restrict__ x,
    const float* __restrict__ Wih0, const float* __restrict__ Whh0,
    const float* __restrict__ bih0, const float* __restrict__ bhh0,
    const float* __restrict__ Wih1, const float* __restrict__ Whh1,
    const float* __restrict__ bih1, const float* __restrict__ bhh1,
    const float* __restrict__ Wfc,  const float* __restrict__ bfc,
    float* __restrict__ out, unsigned* __restrict__ ws)
{
  __shared__ f16x8 w2h_lds[4*4*8*64];   // Whh1 slice, frag order, 128 KB

  const int b   = blockIdx.x;
  const int j   = b & 3;                // group member: h-cols [64j, 64j+64)
  const int grp = b >> 2;
  const int tid = threadIdx.x;
  const int w   = tid >> 6;
  const int L   = tid & 63;
  const int p   = L & 15;
  const int gq  = L >> 4;
  const int R0  = grp * NB;

  unsigned* h0r = ws;                   // [3][NGRP][NB][256] dwords
  unsigned* h1r = ws + 3*(size_t)SLOTD;

  // ---- weights: Whh0, Wih1 -> registers; Whh1 -> LDS (validated r2-r7)
  f16x8 W1[4][8], W2i[4][8];
  float bs1[4], wx0[4], bs2[4];
#pragma unroll
  for (int gate=0; gate<4; ++gate){
    const int gr = 256*gate + 64*j + 16*w + p;
    const float* r0 = Whh0 + (size_t)gr*Hdim;
    const float* r1 = Wih1 + (size_t)gr*Hdim;
    const float* r2 = Whh1 + (size_t)gr*Hdim;
#pragma unroll
    for (int kc=0; kc<8; ++kc){
      W1[gate][kc]  = load_wfrag(r0, 32*kc + 4*gq);
      W2i[gate][kc] = load_wfrag(r1, 32*kc + 4*gq);
      w2h_lds[((w*4+gate)*8+kc)*64 + L] = load_wfrag(r2, 32*kc + 4*gq);
    }
    bs1[gate] = bih0[gr] + bhh0[gr];
    wx0[gate] = Wih0[gr];
    bs2[gate] = bih1[gr] + bhh1[gr];
  }
  // each wave reads only its own w2h_lds region: no barrier needed

  const int myq = 64*j + 16*w + p;      // (2) PLAIN column position
  const int grpoff = grp * (NB*256);
  const int laneoff = grpoff + p*256 + 4*gq;   // frag read base (plain)
  const int rowoff  = grpoff + p*256;          // pre-poll row base
  float c0[4] = {0,0,0,0};
  float c1[4] = {0,0,0,0};

  for (int t=0; t<=Tdim; ++t){
    f16x8 a0[8], a1[8];
    const bool has_h1 = (t > 1);

    // ---- h0(t-1): pre-poll then full validated read
    if (t){
      const unsigned* s0row = h0r + (size_t)((t-1)%3)*SLOTD + rowoff;
      prepoll(s0row, TAGOF(t-1), p);
      const unsigned* s0 = h0r + (size_t)((t-1)%3)*SLOTD + laneoff;
      long it = 0; bool ok;
      do { ok = try_read_frags(s0, TAGOF(t-1), a0); } while (!ok && ++it < 60000);
    }

    // ================= layer 1, step t =================
    if (t < Tdim){
      float xv[4];
#pragma unroll
      for (int u=0; u<4; ++u) xv[u] = x[(size_t)(R0 + 4*gq + u)*Tdim + t];
      f32x4 acc[4];
#pragma unroll
      for (int gate=0; gate<4; ++gate)
#pragma unroll
        for (int u=0; u<4; ++u) acc[gate][u] = bs1[gate] + xv[u]*wx0[gate];
      if (t){
#pragma unroll
        for (int kc=0; kc<8; ++kc)
#pragma unroll
          for (int gate=0; gate<4; ++gate)
            acc[gate] = __builtin_amdgcn_mfma_f32_16x16x32_f16(a0[kc], W1[gate][kc], acc[gate], 0,0,0);
      }
      unsigned* dst = h0r + (size_t)(t%3)*SLOTD + grpoff + myq;
      const unsigned tg = TAGOF(t) << 16;
#pragma unroll
      for (int u=0; u<4; ++u){
        float iv = sigm(acc[0][u]);
        float fv = sigm(acc[1][u]);
        float gv = tanh_fast(acc[2][u]);
        float ov = sigm(acc[3][u]);
        c0[u] = fv*c0[u] + iv*gv;
        st_mall(&dst[(4*gq+u)*256], tg | __builtin_bit_cast(unsigned short, (_Float16)(ov*tanh_fast(c0[u]))));
      }
    }

    // ================= layer 2, step t-1 =================
    if (t){
      f32x4 acc[4];
#pragma unroll
      for (int gate=0; gate<4; ++gate)
#pragma unroll
        for (int u=0; u<4; ++u) acc[gate][u] = bs2[gate];
      // (3) a0-dependent W2i chain first: hides the h1 poll behind it
#pragma unroll
      for (int kc=0; kc<8; ++kc)
#pragma unroll
        for (int gate=0; gate<4; ++gate)
          acc[gate] = __builtin_amdgcn_mfma_f32_16x16x32_f16(a0[kc], W2i[gate][kc], acc[gate], 0,0,0);
      if (has_h1){
        const unsigned* s1row = h1r + (size_t)((t-2)%3)*SLOTD + rowoff;
        prepoll(s1row, TAGOF(t-2), p);
        const unsigned* s1 = h1r + (size_t)((t-2)%3)*SLOTD + laneoff;
        long it = 0; bool ok;
        do { ok = try_read_frags(s1, TAGOF(t-2), a1); } while (!ok && ++it < 60000);
#pragma unroll
        for (int kc=0; kc<8; ++kc)
#pragma unroll
          for (int gate=0; gate<4; ++gate){
            f16x8 wf = w2h_lds[((w*4+gate)*8+kc)*64 + L];
            acc[gate] = __builtin_amdgcn_mfma_f32_16x16x32_f16(a1[kc], wf, acc[gate], 0,0,0);
          }
      }
      unsigned* dst1 = h1r + (size_t)((t-1)%3)*SLOTD + grpoff + myq;
      const unsigned tg1 = TAGOF(t-1) << 16;
#pragma unroll
      for (int u=0; u<4; ++u){
        float iv = sigm(acc[0][u]);
        float fv = sigm(acc[1][u]);
        float gv = tanh_fast(acc[2][u]);
        float ov = sigm(acc[3][u]);
        c1[u] = fv*c1[u] + iv*gv;
        st_mall(&dst1[(4*gq+u)*256], tg1 | __builtin_bit_cast(unsigned short, (_Float16)(ov*tanh_fast(c1[u]))));
      }
    }
  }

  // ---- FC epilogue: member 0, wave 0 reduces the group's 16 batch rows
  if (j == 0 && w == 0){
    const unsigned* src = h1r + (size_t)((Tdim-1)%3)*SLOTD + laneoff;
    const unsigned want = TAGOF(Tdim-1);
    f16x8 hf[8];
    long it = 0; bool ok;
    do { ok = try_read_frags(src, want, hf); } while (!ok && ++it < 60000);
    float s = 0.0f;
#pragma unroll
    for (int kc=0; kc<8; ++kc)
#pragma unroll
      for (int e=0; e<8; ++e){
        int k = 32*kc + 4*gq + (e<4 ? e : 12+e);   // plain layout k
        s += (float)hf[kc][e] * Wfc[k];
      }
    s += __shfl_xor(s, 16);
    s += __shfl_xor(s, 32);
    if (gq == 0) out[R0 + p] = s + bfc[0];
  }
}

extern "C" void kernel_launch(void* const* d_in, const int* in_sizes, int n_in,
                              void* d_out, int out_size, void* d_ws, size_t ws_size,
                              hipStream_t stream) {
  // tags self-validate against 0xAA poison (1..513 != 0xAAAA); no memset,
  // no sync APIs (graph-capture safe)
  lstm2_r8<<<dim3(128), dim3(256), 0, stream>>>(
      (const float*)d_in[0],
      (const float*)d_in[1], (const float*)d_in[2],
      (const float*)d_in[3], (const float*)d_in[4],
      (const float*)d_in[5], (const float*)d_in[6],
      (const float*)d_in[7], (const float*)d_in[8],
      (const float*)d_in[9], (const float*)d_in[10],
      (float*)d_out, (unsigned*)d_ws);
}